// Round 4
// baseline (28.691 us; speedup 1.0000x reference)
//
#include <hip/hip_runtime.h>
#include <cstdint>

#define TPB 256
#define LOG2E 1.4426950408889634f
#define LN2   0.69314718055994531f
#define RS    36                    // LDS row stride in u32 (32 data + 4 pad)
#define VALID_LIM (1024u << 16)     // packed < this  <=>  element is valid

__global__ __launch_bounds__(TPB, 4)
void pl_main(const float* __restrict__ scores,
             const int* __restrict__ ranks,
             const int* __restrict__ mask,
             float* __restrict__ partials,
             int B)
{
    const int tid = threadIdx.x;

    // packed tile: pb[rowLocal*RS + j] = (key11 << 16) | bf16(e_j)
    // key = m*1024 + r*32 + j  (unique 11-bit stable-sort key; valid < 1024)
    __shared__ unsigned pb[TPB * RS];   // 36,864 B -> 4 blocks/CU

    const size_t tile4 = (size_t)blockIdx.x * (TPB * 8);   // float4/int4 base
    const size_t tot4  = (size_t)B * 8;

    const float4* sp = reinterpret_cast<const float4*>(scores) + tile4;
    const int4*   rp = reinterpret_cast<const int4*>(ranks)   + tile4;
    const int4*   mp = reinterpret_cast<const int4*>(mask)    + tile4;

    // ---- stage: lane-consecutive (fully coalesced) loads; pack; LDS write
    #pragma unroll
    for (int i = 0; i < 8; ++i) {
        const int f = i * TPB + tid;            // float4 index in tile
        if (tile4 + f < tot4) {
            const float4 sv = sp[f];
            const int4   rv = rp[f];
            const int4   qv = mp[f];
            const int rowL = f >> 3;
            const int j0   = (f & 7) * 4;

            uint4 w;
            {   // component x
                const float e = __builtin_amdgcn_exp2f(sv.x * LOG2E);
                const unsigned b = __builtin_bit_cast(unsigned, e);
                const unsigned b16 = (b + 0x7FFFu + ((b >> 16) & 1u)) >> 16;   // RNE
                w.x = ((unsigned)((qv.x << 10) + (rv.x << 5) + (j0 + 0)) << 16) | b16;
            }
            {   // y
                const float e = __builtin_amdgcn_exp2f(sv.y * LOG2E);
                const unsigned b = __builtin_bit_cast(unsigned, e);
                const unsigned b16 = (b + 0x7FFFu + ((b >> 16) & 1u)) >> 16;
                w.y = ((unsigned)((qv.y << 10) + (rv.y << 5) + (j0 + 1)) << 16) | b16;
            }
            {   // z
                const float e = __builtin_amdgcn_exp2f(sv.z * LOG2E);
                const unsigned b = __builtin_bit_cast(unsigned, e);
                const unsigned b16 = (b + 0x7FFFu + ((b >> 16) & 1u)) >> 16;
                w.z = ((unsigned)((qv.z << 10) + (rv.z << 5) + (j0 + 2)) << 16) | b16;
            }
            {   // w
                const float e = __builtin_amdgcn_exp2f(sv.w * LOG2E);
                const unsigned b = __builtin_bit_cast(unsigned, e);
                const unsigned b16 = (b + 0x7FFFu + ((b >> 16) & 1u)) >> 16;
                w.w = ((unsigned)((qv.w << 10) + (rv.w << 5) + (j0 + 3)) << 16) | b16;
            }
            // aligned b128 store; start bank 4*((rowL+c)&7) is uniform 8/bank
            *reinterpret_cast<uint4*>(&pb[rowL * RS + j0]) = w;
        }
    }
    __syncthreads();

    // ---- per-row phase: thread tid owns rowLocal = tid
    float per_row = 0.0f, cnt = 0.0f;
    const int row = blockIdx.x * TPB + tid;

    if (row < B) {
        unsigned U[32];
        #pragma unroll
        for (int c = 0; c < 8; ++c) {
            const uint4 v = *reinterpret_cast<const uint4*>(&pb[tid * RS + c * 4]);
            U[c*4+0] = v.x; U[c*4+1] = v.y; U[c*4+2] = v.z; U[c*4+3] = v.w;
        }

        // payload-carrying bitonic sort on packed u32 (keys unique -> order
        // decided by high bits); fully unrolled, 2 VALU per comparator
        #pragma unroll
        for (int kk = 2; kk <= 32; kk <<= 1) {
            #pragma unroll
            for (int jj = kk >> 1; jj > 0; jj >>= 1) {
                #pragma unroll
                for (int i = 0; i < 32; ++i) {
                    const int l = i ^ jj;
                    if (l > i) {
                        const unsigned a = U[i], b = U[l];
                        const unsigned mn = a < b ? a : b;
                        const unsigned mh = a < b ? b : a;
                        if ((i & kk) == 0) { U[i] = mn; U[l] = mh; }
                        else               { U[i] = mh; U[l] = mn; }
                    }
                }
            }
        }

        // suffix sums + grouped logs; valid entries are exactly p < n
        int   n = 0;
        float t = 0.0f, lsum = 0.0f;
        #pragma unroll
        for (int g = 7; g >= 0; --g) {
            float pT = 1.0f, pE = 1.0f;
            #pragma unroll
            for (int q = 3; q >= 0; --q) {
                const int p = 4*g + q;
                const bool v = (U[p] < VALID_LIM);
                const float e = __builtin_bit_cast(float, U[p] << 16);  // bf16->f32
                n  += v ? 1 : 0;
                t  += v ? e : 0.0f;
                pT *= v ? t : 1.0f;
                pE *= v ? e : 1.0f;
            }
            lsum += __builtin_amdgcn_logf(pT) - __builtin_amdgcn_logf(pE);  // hw log2
        }

        if (n >= 2) {
            per_row = (LN2 * lsum) / (float)n;
            cnt = 1.0f;
        }
    }

    // ---- block reduction
    #pragma unroll
    for (int d = 32; d >= 1; d >>= 1) {
        per_row += __shfl_xor(per_row, d, 64);
        cnt     += __shfl_xor(cnt,     d, 64);
    }
    __shared__ float rbuf[8];
    if ((tid & 63) == 0) {
        rbuf[(tid >> 6)]     = per_row;
        rbuf[4 + (tid >> 6)] = cnt;
    }
    __syncthreads();
    if (tid == 0) {
        partials[2*blockIdx.x]     = (rbuf[0] + rbuf[1]) + (rbuf[2] + rbuf[3]);
        partials[2*blockIdx.x + 1] = (rbuf[4] + rbuf[5]) + (rbuf[6] + rbuf[7]);
    }
}

__global__ __launch_bounds__(256)
void pl_final(const float* __restrict__ partials, int nb, float* __restrict__ out)
{
    const int tid = threadIdx.x;
    float s = 0.0f, c = 0.0f;
    for (int i = tid; i < nb; i += 256) {
        s += partials[2*i];
        c += partials[2*i + 1];
    }
    #pragma unroll
    for (int d = 32; d >= 1; d >>= 1) {
        s += __shfl_xor(s, d, 64);
        c += __shfl_xor(c, d, 64);
    }
    __shared__ float sb[8];
    if ((tid & 63) == 0) {
        sb[tid >> 6]       = s;
        sb[4 + (tid >> 6)] = c;
    }
    __syncthreads();
    if (tid == 0) {
        const float S = sb[0] + sb[1] + sb[2] + sb[3];
        const float C = sb[4] + sb[5] + sb[6] + sb[7];
        out[0] = S / fmaxf(C, 1.0f);
    }
}

extern "C" void kernel_launch(void* const* d_in, const int* in_sizes, int n_in,
                              void* d_out, int out_size, void* d_ws, size_t ws_size,
                              hipStream_t stream)
{
    const float* scores = (const float*)d_in[0];
    const int*   ranks  = (const int*)d_in[1];
    const int*   mask   = (const int*)d_in[2];

    const int B  = in_sizes[0] / 32;
    const int nb = (B + TPB - 1) / TPB;

    float* partials = (float*)d_ws;  // nb * 2 floats

    pl_main<<<nb, TPB, 0, stream>>>(scores, ranks, mask, partials, B);
    pl_final<<<1, 256, 0, stream>>>(partials, nb, (float*)d_out);
}